// Round 6
// baseline (140.023 us; speedup 1.0000x reference)
//
#include <hip/hip_runtime.h>

#define B_DIM   2048
#define IN_DIM  4096
#define OUT_DIM 4096
#define FAN     64

// R6: R3's proven structure (8-row tiles, ds_read_b128 gather = 8 MACs/read,
// 2-barrier K-loop, DMA staging) with DOUBLE the occupancy: 512-thread blocks,
// grid 64 bsegs x 8 oblocks = 512 blocks -> 2 blocks/CU (128 KB LDS), 16
// waves/CU vs R3's 8. R5 lesson: b64 half-tiles raise the LDS instr floor 2x —
// never trade gather width for pipelining. R2/R4 lesson: keep register state
// non-loop-carried and small; gather addrs packed 2x16-bit per VGPR (-32 regs)
// so the 128-VGPR cap of __launch_bounds__(512,2) doesn't spill.
//
// Packed layout (d_ws): tile t = batch rows 8t..8t+7. Cell (t,c) = 16 B:
// dword k = bf16 rows (2k, 2k+1) of column c. ds_read_b128 at c*16 -> 8 rows.

typedef float v2f __attribute__((ext_vector_type(2)));

__device__ __forceinline__ unsigned bf16_rne(float f) {
    unsigned u = __float_as_uint(f);
    return (u + 0x7fffu + ((u >> 16) & 1u)) >> 16;   // round-to-nearest-even bf16
}

// ---------------- Phase 1: pack fp32 -> bf16 8-row cells ----------------
__global__ __launch_bounds__(256) void pack_kernel(
    const float* __restrict__ input, uint4* __restrict__ wsp)
{
    const int idx = blockIdx.x * 256 + threadIdx.x;   // [0, 524288): 2 cells each
    const int t   = idx >> 11;                        // tile [0,256)
    const int c0  = (idx & 2047) << 1;                // column pair [0,4096)

    const float* p = input + (size_t)t * 8 * IN_DIM + c0;
    const float2 r0 = *reinterpret_cast<const float2*>(p + 0 * IN_DIM);
    const float2 r1 = *reinterpret_cast<const float2*>(p + 1 * IN_DIM);
    const float2 r2 = *reinterpret_cast<const float2*>(p + 2 * IN_DIM);
    const float2 r3 = *reinterpret_cast<const float2*>(p + 3 * IN_DIM);
    const float2 r4 = *reinterpret_cast<const float2*>(p + 4 * IN_DIM);
    const float2 r5 = *reinterpret_cast<const float2*>(p + 5 * IN_DIM);
    const float2 r6 = *reinterpret_cast<const float2*>(p + 6 * IN_DIM);
    const float2 r7 = *reinterpret_cast<const float2*>(p + 7 * IN_DIM);

    uint4 a, b;
    a.x = bf16_rne(r0.x) | (bf16_rne(r1.x) << 16);
    a.y = bf16_rne(r2.x) | (bf16_rne(r3.x) << 16);
    a.z = bf16_rne(r4.x) | (bf16_rne(r5.x) << 16);
    a.w = bf16_rne(r6.x) | (bf16_rne(r7.x) << 16);
    b.x = bf16_rne(r0.y) | (bf16_rne(r1.y) << 16);
    b.y = bf16_rne(r2.y) | (bf16_rne(r3.y) << 16);
    b.z = bf16_rne(r4.y) | (bf16_rne(r5.y) << 16);
    b.w = bf16_rne(r6.y) | (bf16_rne(r7.y) << 16);

    uint4* q = wsp + (size_t)t * IN_DIM + c0;
    q[0] = a;
    q[1] = b;
}

// ---------------- Phase 2: gather + accumulate ----------------
__global__ __launch_bounds__(512, 2) void condensed_kernel(
    const uint4* __restrict__ wsp,
    const float* __restrict__ weight,
    const float* __restrict__ bias,
    const int*   __restrict__ mask,
    float*       __restrict__ out)
{
    __shared__ __align__(16) uint4 lds[IN_DIM];       // 64 KB: one 8-row tile

    const int tid   = threadIdx.x;                    // [0,512)
    const int o     = blockIdx.y * 512 + tid;
    const int bseg  = blockIdx.x * 32;                // 32 batch rows per block
    const int tbase = bseg >> 3;                      // 4 tiles per block

    // ---- idx -> packed LDS byte addresses (2 x 16-bit / reg) + weights ----
    unsigned paddr[FAN / 2];
    float    wv[FAN];
    {
        const int4*   mv = reinterpret_cast<const int4*>(mask)     + o * (FAN / 4);
        const float4* wp = reinterpret_cast<const float4*>(weight) + o * (FAN / 4);
        #pragma unroll
        for (int j = 0; j < FAN / 4; ++j) {
            int4   m4 = mv[j];
            float4 w4 = wp[j];
            paddr[2*j+0] = ((unsigned)m4.x << 4) | ((unsigned)m4.y << 20);
            paddr[2*j+1] = ((unsigned)m4.z << 4) | ((unsigned)m4.w << 20);
            wv[4*j+0] = w4.x;
            wv[4*j+1] = w4.y;
            wv[4*j+2] = w4.z;
            wv[4*j+3] = w4.w;
        }
    }
    const float bv = bias[o];
    const char* ldsb = reinterpret_cast<const char*>(lds);

    #pragma unroll
    for (int bt = 0; bt < 4; ++bt) {                  // 4 tiles x 8 rows = 32 rows
        __syncthreads();                              // previous tile's readers done

        // ---- stage 64 KB tile: contiguous DMA, lane-contiguous dst ----
        const uint4* src = wsp + (size_t)(tbase + bt) * IN_DIM + tid;
        #pragma unroll
        for (int it = 0; it < 8; ++it) {
            __builtin_amdgcn_global_load_lds(
                (const __attribute__((address_space(1))) unsigned*)(src + it * 512),
                (__attribute__((address_space(3))) unsigned*)(lds + it * 512 + tid),
                16, 0, 0);
        }

        __syncthreads();                              // drains vmcnt -> LDS valid

        // ---- gather + accumulate: 64 x ds_read_b128, 8 rows each ----
        v2f a01 = {0.f, 0.f}, a23 = {0.f, 0.f}, a45 = {0.f, 0.f}, a67 = {0.f, 0.f};
        #pragma unroll
        for (int jj = 0; jj < FAN / 2; ++jj) {
            const unsigned pa = paddr[jj];
            const uint4 g0 = *reinterpret_cast<const uint4*>(ldsb + (pa & 0xffffu));
            const uint4 g1 = *reinterpret_cast<const uint4*>(ldsb + (pa >> 16));
            {
                const v2f w2 = {wv[2*jj+0], wv[2*jj+0]};
                v2f v;
                v.x = __uint_as_float(g0.x << 16);
                v.y = __uint_as_float(g0.x & 0xffff0000u);
                a01 = __builtin_elementwise_fma(v, w2, a01);
                v.x = __uint_as_float(g0.y << 16);
                v.y = __uint_as_float(g0.y & 0xffff0000u);
                a23 = __builtin_elementwise_fma(v, w2, a23);
                v.x = __uint_as_float(g0.z << 16);
                v.y = __uint_as_float(g0.z & 0xffff0000u);
                a45 = __builtin_elementwise_fma(v, w2, a45);
                v.x = __uint_as_float(g0.w << 16);
                v.y = __uint_as_float(g0.w & 0xffff0000u);
                a67 = __builtin_elementwise_fma(v, w2, a67);
            }
            {
                const v2f w2 = {wv[2*jj+1], wv[2*jj+1]};
                v2f v;
                v.x = __uint_as_float(g1.x << 16);
                v.y = __uint_as_float(g1.x & 0xffff0000u);
                a01 = __builtin_elementwise_fma(v, w2, a01);
                v.x = __uint_as_float(g1.y << 16);
                v.y = __uint_as_float(g1.y & 0xffff0000u);
                a23 = __builtin_elementwise_fma(v, w2, a23);
                v.x = __uint_as_float(g1.z << 16);
                v.y = __uint_as_float(g1.z & 0xffff0000u);
                a45 = __builtin_elementwise_fma(v, w2, a45);
                v.x = __uint_as_float(g1.w << 16);
                v.y = __uint_as_float(g1.w & 0xffff0000u);
                a67 = __builtin_elementwise_fma(v, w2, a67);
            }
        }

        // ---- write 8 outputs (coalesced across 512 threads) ----
        float* op = out + (size_t)(bseg + bt * 8) * OUT_DIM + o;
        op[0 * OUT_DIM] = a01.x + bv;
        op[1 * OUT_DIM] = a01.y + bv;
        op[2 * OUT_DIM] = a23.x + bv;
        op[3 * OUT_DIM] = a23.y + bv;
        op[4 * OUT_DIM] = a45.x + bv;
        op[5 * OUT_DIM] = a45.y + bv;
        op[6 * OUT_DIM] = a67.x + bv;
        op[7 * OUT_DIM] = a67.y + bv;
    }
}

extern "C" void kernel_launch(void* const* d_in, const int* in_sizes, int n_in,
                              void* d_out, int out_size, void* d_ws, size_t ws_size,
                              hipStream_t stream) {
    const float* input  = (const float*)d_in[0];
    const float* weight = (const float*)d_in[1];
    const float* bias   = (const float*)d_in[2];
    const int*   mask   = (const int*)d_in[3];
    float*       out    = (float*)d_out;
    uint4*       wsp    = (uint4*)d_ws;               // needs 16 MiB

    pack_kernel<<<2048, 256, 0, stream>>>(input, wsp);
    dim3 grid(64, 8);    // 512 blocks, 512 thr: 2 blocks/CU, 16 waves/CU
    condensed_kernel<<<grid, 512, 0, stream>>>(wsp, weight, bias, mask, out);
}